// Round 2
// baseline (2943.201 us; speedup 1.0000x reference)
//
#include <hip/hip_runtime.h>

#define D 128
#define BROWS 64        // rows per bucket
#define BSHIFT 6        // log2(BROWS)
#define COLBITS 17      // N <= 131072
#define COLMASK 0x1FFFF

// ---------- Phase 1: bucket histogram with LDS pre-aggregation ----------
__global__ void k_hist(const int* __restrict__ rows, int E,
                       int* __restrict__ counts, int nb) {
    extern __shared__ int h[];   // nb ints
    for (int i = threadIdx.x; i < nb; i += blockDim.x) h[i] = 0;
    __syncthreads();
    int stride = gridDim.x * blockDim.x;
    for (int e = blockIdx.x * blockDim.x + threadIdx.x; e < E; e += stride)
        atomicAdd(&h[rows[e] >> BSHIFT], 1);
    __syncthreads();
    for (int i = threadIdx.x; i < nb; i += blockDim.x) {
        int v = h[i];
        if (v) atomicAdd(&counts[i], v);
    }
}

// ---------- Phase 2: single-block exclusive scan (nb <= 2048) ----------
__global__ void k_scan(const int* __restrict__ counts, int nb, int E,
                       int* __restrict__ offsets, int* __restrict__ cursor) {
    __shared__ int s[1024];
    int t = threadIdx.x;
    int a = (2 * t     < nb) ? counts[2 * t]     : 0;
    int b = (2 * t + 1 < nb) ? counts[2 * t + 1] : 0;
    int pair = a + b;
    s[t] = pair;
    __syncthreads();
    for (int off = 1; off < 1024; off <<= 1) {
        int v = (t >= off) ? s[t - off] : 0;
        __syncthreads();
        s[t] += v;
        __syncthreads();
    }
    int excl = s[t] - pair;
    if (2 * t < nb)     { offsets[2 * t]     = excl;     cursor[2 * t]     = excl; }
    if (2 * t + 1 < nb) { offsets[2 * t + 1] = excl + a; cursor[2 * t + 1] = excl + a; }
    if (t == 0) offsets[nb] = E;
}

// ---------- Phase 3: scatter packed (rowlow|col, val) into bucket regions ----------
__global__ void k_scatter(const int* __restrict__ rows, const int* __restrict__ cols,
                          const float* __restrict__ vals, int E,
                          int* __restrict__ cursor, int2* __restrict__ sorted) {
    int stride = gridDim.x * blockDim.x;
    for (int e = blockIdx.x * blockDim.x + threadIdx.x; e < E; e += stride) {
        int r = rows[e];
        int b = r >> BSHIFT;
        int pos = atomicAdd(&cursor[b], 1);
        unsigned packed = ((unsigned)(r & (BROWS - 1)) << COLBITS) | (unsigned)cols[e];
        sorted[pos] = make_int2((int)packed, __float_as_int(vals[e]));
    }
}

// ---------- Phase 4: one workgroup per bucket, 32KB LDS accumulator ----------
__global__ __launch_bounds__(256) void k_bucket(const int2* __restrict__ sorted,
                                                const int* __restrict__ offsets,
                                                const float* __restrict__ emb,
                                                float* __restrict__ out, int N) {
    __shared__ float acc[BROWS * D];              // 32 KB
    float4* acc4 = (float4*)acc;
    for (int i = threadIdx.x; i < BROWS * D / 4; i += 256)
        acc4[i] = make_float4(0.f, 0.f, 0.f, 0.f);
    __syncthreads();

    int b    = blockIdx.x;
    int beg  = offsets[b];
    int end  = offsets[b + 1];
    int wid  = threadIdx.x >> 6;
    int lane = threadIdx.x & 63;

    for (int i = beg + wid * 4; i < end; i += 16) {
        int n = end - i;
        // zero-val padding: col 0, val 0.0f contributes exactly nothing
        int2 r0 = sorted[i];
        int2 r1 = (n > 1) ? sorted[i + 1] : make_int2(0, 0);
        int2 r2 = (n > 2) ? sorted[i + 2] : make_int2(0, 0);
        int2 r3 = (n > 3) ? sorted[i + 3] : make_int2(0, 0);

        int c0 = r0.x & COLMASK, l0 = (r0.x >> COLBITS) & (BROWS - 1);
        int c1 = r1.x & COLMASK, l1 = (r1.x >> COLBITS) & (BROWS - 1);
        int c2 = r2.x & COLMASK, l2 = (r2.x >> COLBITS) & (BROWS - 1);
        int c3 = r3.x & COLMASK, l3 = (r3.x >> COLBITS) & (BROWS - 1);
        float v0 = __int_as_float(r0.y), v1 = __int_as_float(r1.y);
        float v2 = __int_as_float(r2.y), v3 = __int_as_float(r3.y);

        // 8 independent coalesced gathers (256B/wave each) for MLP
        float e00 = emb[(size_t)c0 * D + lane];
        float e01 = emb[(size_t)c0 * D + 64 + lane];
        float e10 = emb[(size_t)c1 * D + lane];
        float e11 = emb[(size_t)c1 * D + 64 + lane];
        float e20 = emb[(size_t)c2 * D + lane];
        float e21 = emb[(size_t)c2 * D + 64 + lane];
        float e30 = emb[(size_t)c3 * D + lane];
        float e31 = emb[(size_t)c3 * D + 64 + lane];

        // conflict-free ds_add_f32 (stride-1 within each instr)
        atomicAdd(&acc[l0 * D + lane],      v0 * e00);
        atomicAdd(&acc[l0 * D + 64 + lane], v0 * e01);
        atomicAdd(&acc[l1 * D + lane],      v1 * e10);
        atomicAdd(&acc[l1 * D + 64 + lane], v1 * e11);
        atomicAdd(&acc[l2 * D + lane],      v2 * e20);
        atomicAdd(&acc[l2 * D + 64 + lane], v2 * e21);
        atomicAdd(&acc[l3 * D + lane],      v3 * e30);
        atomicAdd(&acc[l3 * D + 64 + lane], v3 * e31);
    }
    __syncthreads();

    // coalesced write of the bucket's contiguous 32KB output region
    size_t rowbase = (size_t)b * BROWS;
    float4* out4 = (float4*)out;
    for (int i = threadIdx.x; i < BROWS * D / 4; i += 256) {
        int row = i >> 5;                         // 32 float4 per row
        if (rowbase + row < (size_t)N)
            out4[rowbase * (D / 4) + i] = acc4[i];
    }
}

// ---------- Fallback: direct atomic scatter-add ----------
__global__ void k_atomic(const int* __restrict__ rows, const int* __restrict__ cols,
                         const float* __restrict__ vals, const float2* __restrict__ emb,
                         float* __restrict__ out, int E) {
    long long g = (long long)blockIdx.x * blockDim.x + threadIdx.x;
    int e    = (int)(g >> 6);
    int lane = (int)(g & 63);
    if (e >= E) return;
    int r = rows[e], c = cols[e];
    float v = vals[e];
    float2 em = emb[(size_t)c * (D / 2) + lane];
    atomicAdd(&out[(size_t)r * D + lane * 2    ], v * em.x);
    atomicAdd(&out[(size_t)r * D + lane * 2 + 1], v * em.y);
}

extern "C" void kernel_launch(void* const* d_in, const int* in_sizes, int n_in,
                              void* d_out, int out_size, void* d_ws, size_t ws_size,
                              hipStream_t stream) {
    const int*   adj  = (const int*)d_in[0];     // [2, E] int32
    const float* vals = (const float*)d_in[1];   // [E] f32
    const float* emb  = (const float*)d_in[2];   // [N, 128] f32
    int E = in_sizes[1];
    int N = in_sizes[2] / D;
    const int* rows = adj;
    const int* cols = adj + E;
    float* out = (float*)d_out;

    int nb = (N + BROWS - 1) / BROWS;

    // workspace layout
    size_t off_sorted  = 0;
    size_t sz_sorted   = (size_t)E * 8;
    size_t off_offsets = (off_sorted + sz_sorted + 15) & ~(size_t)15;
    size_t sz_offsets  = (size_t)(nb + 1) * 4;
    size_t off_cursor  = (off_offsets + sz_offsets + 15) & ~(size_t)15;
    size_t sz_cursor   = (size_t)nb * 4;
    size_t off_counts  = (off_cursor + sz_cursor + 15) & ~(size_t)15;
    size_t sz_counts   = (size_t)nb * 4;
    size_t need        = off_counts + sz_counts;

    if (ws_size >= need && nb <= 2048 && N <= (1 << COLBITS)) {
        char* ws = (char*)d_ws;
        int2* sorted  = (int2*)(ws + off_sorted);
        int*  offsets = (int*) (ws + off_offsets);
        int*  cursor  = (int*) (ws + off_cursor);
        int*  counts  = (int*) (ws + off_counts);

        hipMemsetAsync(counts, 0, sz_counts, stream);
        k_hist   <<<256, 256, (size_t)nb * 4, stream>>>(rows, E, counts, nb);
        k_scan   <<<1, 1024, 0, stream>>>(counts, nb, E, offsets, cursor);
        k_scatter<<<1024, 256, 0, stream>>>(rows, cols, vals, E, cursor, sorted);
        k_bucket <<<nb, 256, 0, stream>>>(sorted, offsets, emb, out, N);
    } else {
        hipMemsetAsync(out, 0, (size_t)out_size * sizeof(float), stream);
        long long tot = (long long)E * 64;
        int blocks = (int)((tot + 255) / 256);
        k_atomic<<<blocks, 256, 0, stream>>>(rows, cols, vals, (const float2*)emb, out, E);
    }
}

// Round 3
// 997.552 us; speedup vs baseline: 2.9504x; 2.9504x over previous
//
#include <hip/hip_runtime.h>

#define D 128
#define BROWS 64
#define BSHIFT 6
#define COLBITS 17
#define COLMASK 0x1FFFF
#define CHUNKS 256
#define CAP 2560

// ---------- emb fp32 -> packed bf16x2 ----------
__global__ void k_cvt(const float2* __restrict__ emb, unsigned* __restrict__ q, int n) {
    int stride = gridDim.x * blockDim.x;
    for (int i = blockIdx.x * blockDim.x + threadIdx.x; i < n; i += stride) {
        float2 f = emb[i];
        unsigned lo = __float_as_uint(f.x), hi = __float_as_uint(f.y);
        lo = (lo + 0x7FFFu + ((lo >> 16) & 1u)) & 0xFFFF0000u;   // RNE to bf16
        hi = (hi + 0x7FFFu + ((hi >> 16) & 1u)) & 0xFFFF0000u;
        q[i] = hi | (lo >> 16);
    }
}

// ---------- Phase 1: per-chunk bucket histogram (LDS only) ----------
__global__ void k_mhist(const int* __restrict__ rows, int E, int CE, int nb,
                        int* __restrict__ M) {
    extern __shared__ int h[];
    int c = blockIdx.x;
    for (int i = threadIdx.x; i < nb; i += 256) h[i] = 0;
    __syncthreads();
    int beg = c * CE, end = min(E, beg + CE);
    for (int e = beg + threadIdx.x; e < end; e += 256)
        atomicAdd(&h[rows[e] >> BSHIFT], 1);
    __syncthreads();
    for (int i = threadIdx.x; i < nb; i += 256) M[(size_t)c * nb + i] = h[i];
}

// ---------- Phase 2: exclusive scan of M transposed (flat f = b*CHUNKS + c) ----------
__global__ void k_mscan(const int* __restrict__ M, int nb, int* __restrict__ O) {
    __shared__ int s[1024];
    int flat = nb * CHUNKS;
    int per = (flat + 1023) >> 10;
    int t = threadIdx.x;
    int base = t * per;
    int sum = 0;
    for (int k = 0; k < per; ++k) {
        int f = base + k;
        if (f < flat) { int b = f >> 8, c = f & 255; sum += M[(size_t)c * nb + b]; }
    }
    s[t] = sum;
    __syncthreads();
    for (int off = 1; off < 1024; off <<= 1) {
        int v = (t >= off) ? s[t - off] : 0;
        __syncthreads();
        s[t] += v;
        __syncthreads();
    }
    int run = s[t] - sum;
    for (int k = 0; k < per; ++k) {
        int f = base + k;
        if (f < flat) {
            int b = f >> 8, c = f & 255;
            int v = M[(size_t)c * nb + b];
            O[f] = run;
            run += v;
        }
    }
}

// ---------- Phase 3: scatter via LDS cursors (no global atomics) ----------
__global__ void k_mscatter(const int* __restrict__ rows, const int* __restrict__ cols,
                           const float* __restrict__ vals, int E, int CE, int nb,
                           const int* __restrict__ O, int2* __restrict__ sorted) {
    extern __shared__ int cur[];
    int c = blockIdx.x;
    for (int b = threadIdx.x; b < nb; b += 256) cur[b] = O[b * CHUNKS + c];
    __syncthreads();
    int beg = c * CE, end = min(E, beg + CE);
    for (int e = beg + threadIdx.x; e < end; e += 256) {
        int r = rows[e];
        int b = r >> BSHIFT;
        int pos = atomicAdd(&cur[b], 1);
        unsigned packed = ((unsigned)(r & (BROWS - 1)) << COLBITS) | (unsigned)cols[e];
        sorted[pos] = make_int2((int)packed, __float_as_int(vals[e]));
    }
}

// ---------- Phase 4: per-bucket LDS counting sort + register accumulation ----------
template <bool BF16>
__global__ __launch_bounds__(256) void k_bucket2(const int2* __restrict__ sorted,
                                                 const int* __restrict__ O,
                                                 const void* __restrict__ embp,
                                                 float2* __restrict__ out,
                                                 int N, int nb, int E) {
    __shared__ int rowcnt[BROWS], rowoff[BROWS], rowcur[BROWS];
    __shared__ int2 rec2[CAP];
    int b   = blockIdx.x;
    int beg = O[b * CHUNKS];
    int end = (b + 1 < nb) ? O[(b + 1) * CHUNKS] : E;
    int wid = threadIdx.x >> 6, lane = threadIdx.x & 63;

    float2 acc[16];
#pragma unroll
    for (int q = 0; q < 16; ++q) acc[q] = make_float2(0.f, 0.f);

    const unsigned* eq = (const unsigned*)embp;
    const float2*   e2 = (const float2*)embp;

    for (int done = beg; done < end; done += CAP) {
        int cnt = min(CAP, end - done);
        if (threadIdx.x < BROWS) rowcnt[threadIdx.x] = 0;
        __syncthreads();
        for (int k = threadIdx.x; k < cnt; k += 256)
            atomicAdd(&rowcnt[(((unsigned)sorted[done + k].x) >> COLBITS) & (BROWS - 1)], 1);
        __syncthreads();
        if (threadIdx.x < 64) {
            int v = rowcnt[lane];
            int incl = v;
#pragma unroll
            for (int off = 1; off < 64; off <<= 1) {
                int u = __shfl_up(incl, off);
                if (lane >= off) incl += u;
            }
            rowoff[lane] = incl - v;
            rowcur[lane] = incl - v;
        }
        __syncthreads();
        for (int k = threadIdx.x; k < cnt; k += 256) {
            int2 r = sorted[done + k];
            int row = (((unsigned)r.x) >> COLBITS) & (BROWS - 1);
            int pos = atomicAdd(&rowcur[row], 1);
            rec2[pos] = r;
        }
        __syncthreads();

#pragma unroll 1
        for (int q = 0; q < 16; ++q) {
            int row = wid * 16 + q;
            int off = rowoff[row], cr = rowcnt[row];
            int j = 0;
            for (; j + 4 <= cr; j += 4) {
                int2 r0 = rec2[off + j], r1 = rec2[off + j + 1];
                int2 r2 = rec2[off + j + 2], r3 = rec2[off + j + 3];
                float v0 = __int_as_float(r0.y), v1 = __int_as_float(r1.y);
                float v2 = __int_as_float(r2.y), v3 = __int_as_float(r3.y);
                if (BF16) {
                    unsigned u0 = eq[(size_t)(r0.x & COLMASK) * 64 + lane];
                    unsigned u1 = eq[(size_t)(r1.x & COLMASK) * 64 + lane];
                    unsigned u2 = eq[(size_t)(r2.x & COLMASK) * 64 + lane];
                    unsigned u3 = eq[(size_t)(r3.x & COLMASK) * 64 + lane];
                    acc[q].x += v0 * __uint_as_float(u0 << 16);
                    acc[q].y += v0 * __uint_as_float(u0 & 0xFFFF0000u);
                    acc[q].x += v1 * __uint_as_float(u1 << 16);
                    acc[q].y += v1 * __uint_as_float(u1 & 0xFFFF0000u);
                    acc[q].x += v2 * __uint_as_float(u2 << 16);
                    acc[q].y += v2 * __uint_as_float(u2 & 0xFFFF0000u);
                    acc[q].x += v3 * __uint_as_float(u3 << 16);
                    acc[q].y += v3 * __uint_as_float(u3 & 0xFFFF0000u);
                } else {
                    float2 e0 = e2[(size_t)(r0.x & COLMASK) * 64 + lane];
                    float2 e1 = e2[(size_t)(r1.x & COLMASK) * 64 + lane];
                    float2 e3 = e2[(size_t)(r3.x & COLMASK) * 64 + lane];
                    float2 e2v = e2[(size_t)(r2.x & COLMASK) * 64 + lane];
                    acc[q].x += v0 * e0.x;  acc[q].y += v0 * e0.y;
                    acc[q].x += v1 * e1.x;  acc[q].y += v1 * e1.y;
                    acc[q].x += v2 * e2v.x; acc[q].y += v2 * e2v.y;
                    acc[q].x += v3 * e3.x;  acc[q].y += v3 * e3.y;
                }
            }
            for (; j < cr; ++j) {
                int2 r0 = rec2[off + j];
                float v0 = __int_as_float(r0.y);
                if (BF16) {
                    unsigned u0 = eq[(size_t)(r0.x & COLMASK) * 64 + lane];
                    acc[q].x += v0 * __uint_as_float(u0 << 16);
                    acc[q].y += v0 * __uint_as_float(u0 & 0xFFFF0000u);
                } else {
                    float2 e0 = e2[(size_t)(r0.x & COLMASK) * 64 + lane];
                    acc[q].x += v0 * e0.x;
                    acc[q].y += v0 * e0.y;
                }
            }
        }
        __syncthreads();
    }

    size_t rowbase = (size_t)b * BROWS;
#pragma unroll 1
    for (int q = 0; q < 16; ++q) {
        size_t row = rowbase + wid * 16 + q;
        if (row < (size_t)N) out[row * 64 + lane] = acc[q];
    }
}

// ---------- Fallback: direct atomic scatter-add ----------
__global__ void k_atomic(const int* __restrict__ rows, const int* __restrict__ cols,
                         const float* __restrict__ vals, const float2* __restrict__ emb,
                         float* __restrict__ out, int E) {
    long long g = (long long)blockIdx.x * blockDim.x + threadIdx.x;
    int e    = (int)(g >> 6);
    int lane = (int)(g & 63);
    if (e >= E) return;
    int r = rows[e], c = cols[e];
    float v = vals[e];
    float2 em = emb[(size_t)c * (D / 2) + lane];
    atomicAdd(&out[(size_t)r * D + lane * 2    ], v * em.x);
    atomicAdd(&out[(size_t)r * D + lane * 2 + 1], v * em.y);
}

extern "C" void kernel_launch(void* const* d_in, const int* in_sizes, int n_in,
                              void* d_out, int out_size, void* d_ws, size_t ws_size,
                              hipStream_t stream) {
    const int*   adj  = (const int*)d_in[0];
    const float* vals = (const float*)d_in[1];
    const float* emb  = (const float*)d_in[2];
    int E = in_sizes[1];
    int N = in_sizes[2] / D;
    const int* rows = adj;
    const int* cols = adj + E;
    float* out = (float*)d_out;

    int nb = (N + BROWS - 1) / BROWS;
    int CE = (E + CHUNKS - 1) / CHUNKS;

    size_t off_sorted = 0;
    size_t sz_sorted  = (size_t)E * 8;
    size_t off_M      = (off_sorted + sz_sorted + 255) & ~(size_t)255;
    size_t sz_M       = (size_t)nb * CHUNKS * 4;
    size_t off_O      = (off_M + sz_M + 255) & ~(size_t)255;
    size_t sz_O       = (size_t)nb * CHUNKS * 4;
    size_t off_q      = (off_O + sz_O + 255) & ~(size_t)255;
    size_t sz_q       = (size_t)N * 64 * 4;
    size_t need_bf16  = off_q + sz_q;
    size_t need_f32   = off_q;

    bool ok = (N <= (1 << COLBITS)) && ((size_t)nb * 4 <= 65536);

    if (ok && ws_size >= need_f32) {
        char* ws = (char*)d_ws;
        int2* sorted = (int2*)(ws + off_sorted);
        int*  M      = (int*)(ws + off_M);
        int*  O      = (int*)(ws + off_O);
        bool  bf16   = (ws_size >= need_bf16);

        if (bf16) {
            unsigned* q = (unsigned*)(ws + off_q);
            k_cvt<<<512, 256, 0, stream>>>((const float2*)emb, q, N * 64);
        }
        k_mhist   <<<CHUNKS, 256, (size_t)nb * 4, stream>>>(rows, E, CE, nb, M);
        k_mscan   <<<1, 1024, 0, stream>>>(M, nb, O);
        k_mscatter<<<CHUNKS, 256, (size_t)nb * 4, stream>>>(rows, cols, vals, E, CE, nb, O, sorted);
        if (bf16) {
            k_bucket2<true><<<nb, 256, 0, stream>>>(sorted, O, (const void*)(ws + off_q),
                                                    (float2*)out, N, nb, E);
        } else {
            k_bucket2<false><<<nb, 256, 0, stream>>>(sorted, O, (const void*)emb,
                                                     (float2*)out, N, nb, E);
        }
    } else {
        hipMemsetAsync(out, 0, (size_t)out_size * sizeof(float), stream);
        long long tot = (long long)E * 64;
        int blocks = (int)((tot + 255) / 256);
        k_atomic<<<blocks, 256, 0, stream>>>(rows, cols, vals, (const float2*)emb, out, E);
    }
}

// Round 5
// 386.735 us; speedup vs baseline: 7.6104x; 2.5794x over previous
//
#include <hip/hip_runtime.h>

#define D 128
#define BROWS 64
#define BSHIFT 6
#define COLBITS 17
#define COLMASK 0x1FFFF
#define CHUNKS 256
#define CAP 2560

// ---------- emb fp32 -> packed bf16x2 ----------
__global__ void k_cvt(const float2* __restrict__ emb, unsigned* __restrict__ q, int n) {
    int stride = gridDim.x * blockDim.x;
    for (int i = blockIdx.x * blockDim.x + threadIdx.x; i < n; i += stride) {
        float2 f = emb[i];
        unsigned lo = __float_as_uint(f.x), hi = __float_as_uint(f.y);
        lo = (lo + 0x7FFFu + ((lo >> 16) & 1u)) & 0xFFFF0000u;   // RNE to bf16
        hi = (hi + 0x7FFFu + ((hi >> 16) & 1u)) & 0xFFFF0000u;
        q[i] = hi | (lo >> 16);
    }
}

// ---------- Phase 1: per-chunk bucket histogram, written TRANSPOSED ----------
// M[b * CHUNKS + c] = #edges of chunk c landing in bucket b
__global__ void k_mhist(const int* __restrict__ rows, int E, int CE, int nb,
                        int* __restrict__ M) {
    extern __shared__ int h[];
    int c = blockIdx.x;
    for (int i = threadIdx.x; i < nb; i += 256) h[i] = 0;
    __syncthreads();
    int beg = c * CE, end = min(E, beg + CE);
    for (int e = beg + threadIdx.x; e < end; e += 256)
        atomicAdd(&h[rows[e] >> BSHIFT], 1);
    __syncthreads();
    for (int i = threadIdx.x; i < nb; i += 256) M[(size_t)i * CHUNKS + c] = h[i];
}

// ---------- Phase 2: hierarchical exclusive scan over flat M (coalesced) ----------
__global__ void k_scan1(const int* __restrict__ M, int flat,
                        int* __restrict__ O, int* __restrict__ bs) {
    __shared__ int s[1024];
    int i = blockIdx.x * 1024 + threadIdx.x;
    int v = (i < flat) ? M[i] : 0;
    s[threadIdx.x] = v;
    __syncthreads();
    for (int off = 1; off < 1024; off <<= 1) {
        int t = (threadIdx.x >= (unsigned)off) ? s[threadIdx.x - off] : 0;
        __syncthreads();
        s[threadIdx.x] += t;
        __syncthreads();
    }
    if (i < flat) O[i] = s[threadIdx.x] - v;
    if (threadIdx.x == 1023) bs[blockIdx.x] = s[1023];
}

__global__ void k_scan2(int* __restrict__ bs, int nblk) {
    __shared__ int s[1024];
    __shared__ int carry;
    if (threadIdx.x == 0) carry = 0;
    __syncthreads();
    for (int base = 0; base < nblk; base += 1024) {
        int i = base + (int)threadIdx.x;
        int v = (i < nblk) ? bs[i] : 0;
        s[threadIdx.x] = v;
        __syncthreads();
        for (int off = 1; off < 1024; off <<= 1) {
            int t = (threadIdx.x >= (unsigned)off) ? s[threadIdx.x - off] : 0;
            __syncthreads();
            s[threadIdx.x] += t;
            __syncthreads();
        }
        int c = carry;
        if (i < nblk) bs[i] = c + s[threadIdx.x] - v;
        __syncthreads();
        if (threadIdx.x == 0) carry = c + s[1023];
        __syncthreads();
    }
}

__global__ void k_scan3(int* __restrict__ O, int flat, const int* __restrict__ bs) {
    int i = blockIdx.x * 1024 + threadIdx.x;
    if (i < flat) O[i] += bs[blockIdx.x];
}

// ---------- Phase 3: scatter via LDS cursors (no global atomics) ----------
__global__ void k_mscatter(const int* __restrict__ rows, const int* __restrict__ cols,
                           const float* __restrict__ vals, int E, int CE, int nb,
                           const int* __restrict__ O, int2* __restrict__ sorted) {
    extern __shared__ int cur[];
    int c = blockIdx.x;
    for (int b = threadIdx.x; b < nb; b += 256) cur[b] = O[b * CHUNKS + c];
    __syncthreads();
    int beg = c * CE, end = min(E, beg + CE);
    for (int e = beg + threadIdx.x; e < end; e += 256) {
        int r = rows[e];
        int b = r >> BSHIFT;
        int pos = atomicAdd(&cur[b], 1);
        unsigned packed = ((unsigned)(r & (BROWS - 1)) << COLBITS) | (unsigned)cols[e];
        if (pos >= 0 && pos < E)                     // defensive: never write OOB
            sorted[pos] = make_int2((int)packed, __float_as_int(vals[e]));
    }
}

// ---------- Phase 4: per-bucket LDS counting sort + register accumulation ----------
template <bool BF16>
__global__ __launch_bounds__(256) void k_bucket2(const int2* __restrict__ sorted,
                                                 const int* __restrict__ O,
                                                 const void* __restrict__ embp,
                                                 float2* __restrict__ out,
                                                 int N, int nb, int E) {
    __shared__ int rowcnt[BROWS], rowoff[BROWS], rowcur[BROWS];
    __shared__ int2 rec2[CAP];
    int b   = blockIdx.x;
    int beg = O[b * CHUNKS];
    int end = (b + 1 < nb) ? O[(b + 1) * CHUNKS] : E;
    // defensive clamps: a corrupted offset must not cause OOB reads
    beg = max(0, min(beg, E));
    end = max(beg, min(end, E));
    int wid = threadIdx.x >> 6, lane = threadIdx.x & 63;

    float2 acc[16];
#pragma unroll
    for (int q = 0; q < 16; ++q) acc[q] = make_float2(0.f, 0.f);

    const unsigned* eq = (const unsigned*)embp;
    const float2*   e2 = (const float2*)embp;

    for (int done = beg; done < end; done += CAP) {
        int cnt = min(CAP, end - done);
        if (threadIdx.x < BROWS) rowcnt[threadIdx.x] = 0;
        __syncthreads();
        for (int k = threadIdx.x; k < cnt; k += 256)
            atomicAdd(&rowcnt[(((unsigned)sorted[done + k].x) >> COLBITS) & (BROWS - 1)], 1);
        __syncthreads();
        if (threadIdx.x < 64) {
            int v = rowcnt[lane];
            int incl = v;
#pragma unroll
            for (int off = 1; off < 64; off <<= 1) {
                int u = __shfl_up(incl, off);
                if (lane >= off) incl += u;
            }
            rowoff[lane] = incl - v;
            rowcur[lane] = incl - v;
        }
        __syncthreads();
        for (int k = threadIdx.x; k < cnt; k += 256) {
            int2 r = sorted[done + k];
            int row = (((unsigned)r.x) >> COLBITS) & (BROWS - 1);
            int pos = atomicAdd(&rowcur[row], 1);
            if (pos >= 0 && pos < CAP) rec2[pos] = r;
        }
        __syncthreads();

#pragma unroll 1
        for (int q = 0; q < 16; ++q) {
            int row = wid * 16 + q;
            int off = rowoff[row], cr = rowcnt[row];
            int j = 0;
            for (; j + 4 <= cr; j += 4) {
                int2 r0 = rec2[off + j], r1 = rec2[off + j + 1];
                int2 r2 = rec2[off + j + 2], r3 = rec2[off + j + 3];
                float v0 = __int_as_float(r0.y), v1 = __int_as_float(r1.y);
                float v2 = __int_as_float(r2.y), v3 = __int_as_float(r3.y);
                if (BF16) {
                    unsigned u0 = eq[(size_t)(r0.x & COLMASK) * 64 + lane];
                    unsigned u1 = eq[(size_t)(r1.x & COLMASK) * 64 + lane];
                    unsigned u2 = eq[(size_t)(r2.x & COLMASK) * 64 + lane];
                    unsigned u3 = eq[(size_t)(r3.x & COLMASK) * 64 + lane];
                    acc[q].x += v0 * __uint_as_float(u0 << 16);
                    acc[q].y += v0 * __uint_as_float(u0 & 0xFFFF0000u);
                    acc[q].x += v1 * __uint_as_float(u1 << 16);
                    acc[q].y += v1 * __uint_as_float(u1 & 0xFFFF0000u);
                    acc[q].x += v2 * __uint_as_float(u2 << 16);
                    acc[q].y += v2 * __uint_as_float(u2 & 0xFFFF0000u);
                    acc[q].x += v3 * __uint_as_float(u3 << 16);
                    acc[q].y += v3 * __uint_as_float(u3 & 0xFFFF0000u);
                } else {
                    float2 e0 = e2[(size_t)(r0.x & COLMASK) * 64 + lane];
                    float2 e1 = e2[(size_t)(r1.x & COLMASK) * 64 + lane];
                    float2 e3 = e2[(size_t)(r3.x & COLMASK) * 64 + lane];
                    float2 e2v = e2[(size_t)(r2.x & COLMASK) * 64 + lane];
                    acc[q].x += v0 * e0.x;  acc[q].y += v0 * e0.y;
                    acc[q].x += v1 * e1.x;  acc[q].y += v1 * e1.y;
                    acc[q].x += v2 * e2v.x; acc[q].y += v2 * e2v.y;
                    acc[q].x += v3 * e3.x;  acc[q].y += v3 * e3.y;
                }
            }
            for (; j < cr; ++j) {
                int2 r0 = rec2[off + j];
                float v0 = __int_as_float(r0.y);
                if (BF16) {
                    unsigned u0 = eq[(size_t)(r0.x & COLMASK) * 64 + lane];
                    acc[q].x += v0 * __uint_as_float(u0 << 16);
                    acc[q].y += v0 * __uint_as_float(u0 & 0xFFFF0000u);
                } else {
                    float2 e0 = e2[(size_t)(r0.x & COLMASK) * 64 + lane];
                    acc[q].x += v0 * e0.x;
                    acc[q].y += v0 * e0.y;
                }
            }
        }
        __syncthreads();
    }

    size_t rowbase = (size_t)b * BROWS;
#pragma unroll 1
    for (int q = 0; q < 16; ++q) {
        size_t row = rowbase + wid * 16 + q;
        if (row < (size_t)N) out[row * 64 + lane] = acc[q];
    }
}

// ---------- Fallback: direct atomic scatter-add ----------
__global__ void k_atomic(const int* __restrict__ rows, const int* __restrict__ cols,
                         const float* __restrict__ vals, const float2* __restrict__ emb,
                         float* __restrict__ out, int E) {
    long long g = (long long)blockIdx.x * blockDim.x + threadIdx.x;
    int e    = (int)(g >> 6);
    int lane = (int)(g & 63);
    if (e >= E) return;
    int r = rows[e], c = cols[e];
    float v = vals[e];
    float2 em = emb[(size_t)c * (D / 2) + lane];
    atomicAdd(&out[(size_t)r * D + lane * 2    ], v * em.x);
    atomicAdd(&out[(size_t)r * D + lane * 2 + 1], v * em.y);
}

extern "C" void kernel_launch(void* const* d_in, const int* in_sizes, int n_in,
                              void* d_out, int out_size, void* d_ws, size_t ws_size,
                              hipStream_t stream) {
    const int*   adj  = (const int*)d_in[0];
    const float* vals = (const float*)d_in[1];
    const float* emb  = (const float*)d_in[2];
    int E = in_sizes[1];
    int N = in_sizes[2] / D;
    const int* rows = adj;
    const int* cols = adj + E;
    float* out = (float*)d_out;

    int nb   = (N + BROWS - 1) / BROWS;
    int CE   = (E + CHUNKS - 1) / CHUNKS;
    int flat = nb * CHUNKS;
    int nblk = (flat + 1023) / 1024;

    size_t off_sorted = 0;
    size_t sz_sorted  = (size_t)E * 8;
    size_t off_M      = (off_sorted + sz_sorted + 255) & ~(size_t)255;
    size_t sz_M       = (size_t)flat * 4;
    size_t off_O      = (off_M + sz_M + 255) & ~(size_t)255;
    size_t sz_O       = (size_t)flat * 4;
    size_t off_bs     = (off_O + sz_O + 255) & ~(size_t)255;
    size_t sz_bs      = (size_t)nblk * 4;
    size_t off_q      = (off_bs + sz_bs + 255) & ~(size_t)255;
    size_t sz_q       = (size_t)N * 64 * 4;
    size_t need_bf16  = off_q + sz_q;
    size_t need_f32   = off_q;

    bool ok = (N <= (1 << COLBITS)) && ((size_t)nb * 4 <= 65536);

    if (ok && ws_size >= need_f32) {
        char* ws = (char*)d_ws;
        int2* sorted = (int2*)(ws + off_sorted);
        int*  M      = (int*)(ws + off_M);
        int*  O      = (int*)(ws + off_O);
        int*  bs     = (int*)(ws + off_bs);
        bool  bf16   = (ws_size >= need_bf16);

        if (bf16) {
            unsigned* q = (unsigned*)(ws + off_q);
            k_cvt<<<512, 256, 0, stream>>>((const float2*)emb, q, N * 64);
        }
        k_mhist   <<<CHUNKS, 256, (size_t)nb * 4, stream>>>(rows, E, CE, nb, M);
        k_scan1   <<<nblk, 1024, 0, stream>>>(M, flat, O, bs);
        k_scan2   <<<1, 1024, 0, stream>>>(bs, nblk);
        k_scan3   <<<nblk, 1024, 0, stream>>>(O, flat, bs);
        k_mscatter<<<CHUNKS, 256, (size_t)nb * 4, stream>>>(rows, cols, vals, E, CE, nb, O, sorted);
        if (bf16) {
            k_bucket2<true><<<nb, 256, 0, stream>>>(sorted, O, (const void*)(ws + off_q),
                                                    (float2*)out, N, nb, E);
        } else {
            k_bucket2<false><<<nb, 256, 0, stream>>>(sorted, O, (const void*)emb,
                                                     (float2*)out, N, nb, E);
        }
    } else {
        hipMemsetAsync(out, 0, (size_t)out_size * sizeof(float), stream);
        long long tot = (long long)E * 64;
        int blocks = (int)((tot + 255) / 256);
        k_atomic<<<blocks, 256, 0, stream>>>(rows, cols, vals, (const float2*)emb, out, E);
    }
}